// Round 1
// baseline (244.567 us; speedup 1.0000x reference)
//
#include <hip/hip_runtime.h>
#include <hip/hip_bf16.h>
#include <stdint.h>

// ContextualLoss forward on MI355X (gfx950).
// B=4, C=256, H=W=64 -> N=4096.
//   S[b,n,m] = <Xn[:,n], Yn[:,m]>  (centered by Y spatial mean, channel-L2-normalized)
//   A_max[n] = 1 / sum_m exp(beta_n * (S[n,m] - smax_n)),  beta_n = 10/(1 - smax_n + 0.001)
//   loss_b   = -log(mean_n A_max[n])
// Two-pass fused kernel: pass1 row-max, pass2 exp-sum (beta depends on row max -> no online form).
// GEMM in bf16 MFMA 16x16x32; abs error on loss ~1e-2 vs threshold 0.11375.

#define Bn 4
#define Cn 256
#define Nn 4096

typedef float  f32x4  __attribute__((ext_vector_type(4)));
typedef __bf16 bf16x8 __attribute__((ext_vector_type(8)));

#define GLD16(gp, lp) __builtin_amdgcn_global_load_lds(                      \
    (const __attribute__((address_space(1))) void*)(gp),                     \
    (__attribute__((address_space(3))) void*)(lp), 16, 0, 0)

// ---------- K1: per-(b,c) spatial mean of Y ----------
__global__ __launch_bounds__(256) void k_mean(const float* __restrict__ Y,
                                              float* __restrict__ ymean) {
  const int bc = blockIdx.x;                       // 0..1023
  const float4* p4 = (const float4*)(Y + (size_t)bc * 4096);
  float s = 0.f;
  #pragma unroll
  for (int i = 0; i < 4; ++i) {
    float4 v = p4[threadIdx.x + i * 256];
    s += (v.x + v.y) + (v.z + v.w);
  }
  #pragma unroll
  for (int m = 1; m < 64; m <<= 1) s += __shfl_xor(s, m);
  __shared__ float part[4];
  if ((threadIdx.x & 63) == 0) part[threadIdx.x >> 6] = s;
  __syncthreads();
  if (threadIdx.x == 0)
    ymean[bc] = (part[0] + part[1] + part[2] + part[3]) * (1.0f / 4096.0f);
}

// ---------- K2: per-(b,n) L2 norms of centered X and Y ----------
__global__ __launch_bounds__(256) void k_norm(const float* __restrict__ X,
                                              const float* __restrict__ Y,
                                              const float* __restrict__ ymean,
                                              float* __restrict__ nX,
                                              float* __restrict__ nY) {
  const int b  = blockIdx.y;
  const int n0 = blockIdx.x * 64;
  const int tn = threadIdx.x & 63;
  const int cg = threadIdx.x >> 6;                 // 4 channel groups
  __shared__ float mu[256];
  __shared__ float px[4][64], py[4][64];
  mu[threadIdx.x] = ymean[b * 256 + threadIdx.x];
  __syncthreads();
  const size_t base = (size_t)b * 256 * 4096 + n0 + tn;
  float sx = 0.f, sy = 0.f;
  for (int c = cg * 64; c < cg * 64 + 64; ++c) {
    float m = mu[c];
    float x = X[base + (size_t)c * 4096] - m;
    float y = Y[base + (size_t)c * 4096] - m;
    sx += x * x;
    sy += y * y;
  }
  px[cg][tn] = sx; py[cg][tn] = sy;
  __syncthreads();
  if (threadIdx.x < 64) {
    float fx = px[0][threadIdx.x] + px[1][threadIdx.x] + px[2][threadIdx.x] + px[3][threadIdx.x];
    float fy = py[0][threadIdx.x] + py[1][threadIdx.x] + py[2][threadIdx.x] + py[3][threadIdx.x];
    nX[b * 4096 + n0 + threadIdx.x] = sqrtf(fx) + 2.220446049250313e-16f;
    nY[b * 4096 + n0 + threadIdx.x] = sqrtf(fy) + 2.220446049250313e-16f;
  }
}

// ---------- K3: center, normalize, transpose [C][N]->[N][C], cast to bf16 ----------
__global__ __launch_bounds__(256) void k_pack(const float* __restrict__ X,
                                              const float* __restrict__ Y,
                                              const float* __restrict__ ymean,
                                              const float* __restrict__ nX,
                                              const float* __restrict__ nY,
                                              __hip_bfloat16* __restrict__ Xp,
                                              __hip_bfloat16* __restrict__ Yp) {
  const int n0 = blockIdx.x * 64, c0 = blockIdx.y * 64, b = blockIdx.z;
  __shared__ float tile[64][65];                   // +1 pad: conflict-free transpose
  __shared__ float mu[64];
  const int t  = threadIdx.x;
  const int tc = t >> 6, tn = t & 63;              // read phase: 4 c-rows x 64 n
  const int oc = t & 63, on = t >> 6;              // write phase: 64 c x 4 n-rows
  if (t < 64) mu[t] = ymean[b * 256 + c0 + t];
  __syncthreads();
  #pragma unroll 4
  for (int i = 0; i < 16; ++i) {
    int cl = i * 4 + tc;
    tile[cl][tn] = X[((size_t)b * 256 + c0 + cl) * 4096 + n0 + tn] - mu[cl];
  }
  __syncthreads();
  #pragma unroll 4
  for (int i = 0; i < 16; ++i) {
    int nl = i * 4 + on;
    float inv = 1.0f / nX[b * 4096 + n0 + nl];
    Xp[((size_t)b * 4096 + n0 + nl) * 256 + c0 + oc] = __float2bfloat16(tile[oc][nl] * inv);
  }
  __syncthreads();
  #pragma unroll 4
  for (int i = 0; i < 16; ++i) {
    int cl = i * 4 + tc;
    tile[cl][tn] = Y[((size_t)b * 256 + c0 + cl) * 4096 + n0 + tn] - mu[cl];
  }
  __syncthreads();
  #pragma unroll 4
  for (int i = 0; i < 16; ++i) {
    int nl = i * 4 + on;
    float inv = 1.0f / nY[b * 4096 + n0 + nl];
    Yp[((size_t)b * 4096 + n0 + nl) * 256 + c0 + oc] = __float2bfloat16(tile[oc][nl] * inv);
  }
}

// ---------- K4: fused two-pass contextual-similarity kernel ----------
// Block: 64 rows (n) x all 4096 cols (m), K=256. 4 waves = 4 col strips of a
// 256-col macro-tile; wave tile 64x64 (4x4 MFMA frags -> 512B LDS/MFMA).
// Y staged per (macro-tile, k-phase 64) as [256][64] bf16 (32KB), double-buffered.
// XOR swizzle byte^=((row&7)<<4) on staging SOURCE + ds_read addr (linear LDS dest).
__global__ __launch_bounds__(256, 1) void k_main(const __hip_bfloat16* __restrict__ Xp,
                                                 const __hip_bfloat16* __restrict__ Yp,
                                                 float* __restrict__ accum) {
  __shared__ __align__(16) __hip_bfloat16 Xs[64 * 256];      // [n][c] 32KB, swizzled
  __shared__ __align__(16) __hip_bfloat16 Ys[2][256 * 64];   // [m][k64] 2x32KB, swizzled
  __shared__ float red[4][64];

  const int tid  = threadIdx.x;
  const int lane = tid & 63;
  const int w    = tid >> 6;          // wave = column strip
  const int g    = lane >> 4;         // k-octet selector
  const int lr   = lane & 15;

  // Bijective XCD remap: HW XCD = blockIdx.x % 8; give each XCD one batch's Y panel (2MB < 4MB L2).
  const int L  = blockIdx.x;
  const int wk = (L & 7) * 32 + (L >> 3);
  const int b  = wk >> 6;
  const int n0 = (wk & 63) << 6;

  const char* Xg = (const char*)(Xp + ((size_t)b * Nn + n0) * Cn);
  const char* Yg = (const char*)(Yp + (size_t)b * Nn * Cn);
  char* XsB = (char*)Xs;

  // Stage X rows once (32KB): linear LDS dest, pre-swizzled global source.
  #pragma unroll
  for (int i = 0; i < 8; ++i) {
    const int off = i * 4096 + tid * 16;
    const int row = off >> 9;
    const int col = (off & 511) ^ ((row & 7) << 4);
    GLD16(Xg + row * 512 + col, XsB + off);
  }

  // phase p in [0,64): mt = p>>2 (256-col macro-tile), kp = p&3 (64-wide k-phase)
  auto stageY = [&](int p) {
    const char* src = Yg + (size_t)(p >> 2) * 256 * 512 + (p & 3) * 128;
    char* dst = (char*)Ys[p & 1];
    #pragma unroll
    for (int i = 0; i < 8; ++i) {
      const int off = i * 4096 + tid * 16;
      const int row = off >> 7;
      const int col = (off & 127) ^ ((row & 7) << 4);
      GLD16(src + (size_t)row * 512 + col, dst + off);
    }
  };

  f32x4 acc[4][4];
  #pragma unroll
  for (int ai = 0; ai < 4; ++ai)
    #pragma unroll
    for (int bj = 0; bj < 4; ++bj)
      acc[ai][bj] = f32x4{0.f, 0.f, 0.f, 0.f};

  auto computePhase = [&](int p) {
    const char* yb = (const char*)Ys[p & 1];
    const int kp = p & 3;
    #pragma unroll
    for (int kk = 0; kk < 2; ++kk) {
      const int kcol = kk * 64 + g * 16;           // byte col within 128B Ys row
      const int acol = kp * 128 + kcol;            // byte col within 512B Xs row
      bf16x8 a[4], bb[4];
      #pragma unroll
      for (int ai = 0; ai < 4; ++ai) {
        const int row = ai * 16 + lr;
        a[ai] = *(const bf16x8*)(XsB + row * 512 + (acol ^ ((row & 7) << 4)));
      }
      #pragma unroll
      for (int bj = 0; bj < 4; ++bj) {
        const int mrow = w * 64 + bj * 16 + lr;
        bb[bj] = *(const bf16x8*)(yb + mrow * 128 + (kcol ^ ((mrow & 7) << 4)));
      }
      #pragma unroll
      for (int ai = 0; ai < 4; ++ai)
        #pragma unroll
        for (int bj = 0; bj < 4; ++bj)
          acc[ai][bj] = __builtin_amdgcn_mfma_f32_16x16x32_bf16(a[ai], bb[bj], acc[ai][bj], 0, 0, 0);
    }
  };

  float rmax[4][4];
  #pragma unroll
  for (int ai = 0; ai < 4; ++ai)
    #pragma unroll
    for (int r = 0; r < 4; ++r) rmax[ai][r] = -3.0e38f;

  // ---------------- pass 1: row max ----------------
  stageY(0);
  asm volatile("s_waitcnt vmcnt(0)" ::: "memory");
  __syncthreads();
  for (int p = 0; p < 64; ++p) {
    if (p < 63) stageY(p + 1);
    computePhase(p);
    if ((p & 3) == 3) {                            // macro-tile boundary: harvest + zero acc
      #pragma unroll
      for (int ai = 0; ai < 4; ++ai)
        #pragma unroll
        for (int r = 0; r < 4; ++r) {
          float m0 = fmaxf(fmaxf(acc[ai][0][r], acc[ai][1][r]),
                           fmaxf(acc[ai][2][r], acc[ai][3][r]));
          rmax[ai][r] = fmaxf(rmax[ai][r], m0);
          acc[ai][0][r] = 0.f; acc[ai][1][r] = 0.f; acc[ai][2][r] = 0.f; acc[ai][3][r] = 0.f;
        }
    }
    asm volatile("s_waitcnt vmcnt(0)" ::: "memory");
    __syncthreads();
  }

  // combine row max across 16 col-lanes, then across 4 waves
  #pragma unroll
  for (int ai = 0; ai < 4; ++ai)
    #pragma unroll
    for (int r = 0; r < 4; ++r) {
      float v = rmax[ai][r];
      #pragma unroll
      for (int m = 1; m < 16; m <<= 1) v = fmaxf(v, __shfl_xor(v, m));
      red[w][ai * 16 + g * 4 + r] = v;             // all lanes in group write same value
    }
  __syncthreads();
  float smax[4][4], be2[4][4];
  #pragma unroll
  for (int ai = 0; ai < 4; ++ai)
    #pragma unroll
    for (int r = 0; r < 4; ++r) {
      const int row = ai * 16 + g * 4 + r;
      float sm = fmaxf(fmaxf(red[0][row], red[1][row]), fmaxf(red[2][row], red[3][row]));
      smax[ai][r] = sm;
      be2[ai][r]  = (10.0f / (1.0f - sm + 0.001f)) * 1.44269504f;  // beta * log2(e)
    }
  __syncthreads();

  // ---------------- pass 2: exp-sum ----------------
  float ssum[4][4];
  #pragma unroll
  for (int ai = 0; ai < 4; ++ai)
    #pragma unroll
    for (int r = 0; r < 4; ++r) ssum[ai][r] = 0.f;

  stageY(0);
  asm volatile("s_waitcnt vmcnt(0)" ::: "memory");
  __syncthreads();
  for (int p = 0; p < 64; ++p) {
    if (p < 63) stageY(p + 1);
    computePhase(p);
    if ((p & 3) == 3) {
      #pragma unroll
      for (int ai = 0; ai < 4; ++ai)
        #pragma unroll
        for (int r = 0; r < 4; ++r) {
          const float be = be2[ai][r], sm = smax[ai][r];
          float e = exp2f(be * (acc[ai][0][r] - sm)) + exp2f(be * (acc[ai][1][r] - sm))
                  + exp2f(be * (acc[ai][2][r] - sm)) + exp2f(be * (acc[ai][3][r] - sm));
          ssum[ai][r] += e;
          acc[ai][0][r] = 0.f; acc[ai][1][r] = 0.f; acc[ai][2][r] = 0.f; acc[ai][3][r] = 0.f;
        }
    }
    asm volatile("s_waitcnt vmcnt(0)" ::: "memory");
    __syncthreads();
  }

  #pragma unroll
  for (int ai = 0; ai < 4; ++ai)
    #pragma unroll
    for (int r = 0; r < 4; ++r) {
      float v = ssum[ai][r];
      #pragma unroll
      for (int m = 1; m < 16; m <<= 1) v += __shfl_xor(v, m);
      red[w][ai * 16 + g * 4 + r] = v;
    }
  __syncthreads();
  if (w == 0) {
    float tot  = red[0][lane] + red[1][lane] + red[2][lane] + red[3][lane];
    float amax = 1.0f / tot;                       // A_max for row `lane`
    #pragma unroll
    for (int m = 1; m < 64; m <<= 1) amax += __shfl_xor(amax, m);
    if (lane == 0) atomicAdd(accum + b, amax);
  }
}

// ---------- K5: loss = -log(mean A_max) ----------
__global__ void k_final(const float* __restrict__ accum, float* __restrict__ out) {
  const int i = threadIdx.x;
  if (i < Bn) out[i] = -logf(accum[i] * (1.0f / (float)Nn));
}

extern "C" void kernel_launch(void* const* d_in, const int* in_sizes, int n_in,
                              void* d_out, int out_size, void* d_ws, size_t ws_size,
                              hipStream_t stream) {
  const float* X = (const float*)d_in[0];
  const float* Y = (const float*)d_in[1];
  float* out = (float*)d_out;
  char* ws = (char*)d_ws;

  // workspace layout (~16.2 MB total)
  float* accum = (float*)ws;                                   // 4 floats (zeroed below)
  float* ymean = (float*)(ws + 256);                           // 1024 floats
  float* nX    = (float*)(ws + 4608);                          // 16384 floats
  float* nY    = (float*)(ws + 4608 + 65536);                  // 16384 floats
  __hip_bfloat16* Xp = (__hip_bfloat16*)(ws + 4608 + 2 * 65536);   // [B][N][C] bf16, 8MB
  __hip_bfloat16* Yp = Xp + (size_t)Bn * Nn * Cn;                  // [B][N][C] bf16, 8MB

  hipMemsetAsync(accum, 0, 64, stream);
  k_mean <<<Bn * Cn, 256, 0, stream>>>(Y, ymean);
  k_norm <<<dim3(Nn / 64, Bn), 256, 0, stream>>>(X, Y, ymean, nX, nY);
  k_pack <<<dim3(Nn / 64, Cn / 64, Bn), 256, 0, stream>>>(X, Y, ymean, nX, nY, Xp, Yp);
  k_main <<<256, 256, 0, stream>>>(Xp, Yp, accum);
  k_final<<<1, 64, 0, stream>>>(accum, out);
}

// Round 2
// 195.235 us; speedup vs baseline: 1.2527x; 1.2527x over previous
//
#include <hip/hip_runtime.h>
#include <hip/hip_bf16.h>
#include <stdint.h>

// ContextualLoss forward, MI355X. B=4, C=256, N=4096.
// S[n,m] = <Xc[:,n],Yc[:,m]> / (|Xc_n||Yc_m|); A_max[n] = 1/sum_m exp(beta_n (S-smax_n));
// beta_n = 10/(1.001 - smax_n); loss_b = -log(mean_n A_max).
// GEMM on centered UNnormalized bf16 (norms folded into epilogue):
//   t = G[n,m] * invny[m];  smax-pass stores rmax = max_m t;  exp-pass uses
//   exponent = lam*t - mu,  lam = beta*invnx*log2e, mu = lam*rmax_glob.
// Two GEMM kernels (pass1 rowmax, pass2 expsum), 512thr/8wave, 2 waves/SIMD,
// 32x32x16 MFMA, counted-vmcnt double-buffered Y staging (T3/T4/T5).

#define Bn 4
#define Cn 256
#define Nn 4096

typedef float  f32x16 __attribute__((ext_vector_type(16)));
typedef __bf16 bf16x8 __attribute__((ext_vector_type(8)));

#define GLD16(gp, lp) __builtin_amdgcn_global_load_lds(                      \
    (const __attribute__((address_space(1))) void*)(gp),                     \
    (__attribute__((address_space(3))) void*)(lp), 16, 0, 0)

#define LDbf(base, off) (*(const bf16x8*)((base) + (off)))

// ---------- K1: per-(b,c) spatial mean of Y ----------
__global__ __launch_bounds__(256) void k_mean(const float* __restrict__ Y,
                                              float* __restrict__ ymean) {
  const int bc = blockIdx.x;                       // 0..1023
  const float4* p4 = (const float4*)(Y + (size_t)bc * 4096);
  float s = 0.f;
  #pragma unroll
  for (int i = 0; i < 4; ++i) {
    float4 v = p4[threadIdx.x + i * 256];
    s += (v.x + v.y) + (v.z + v.w);
  }
  #pragma unroll
  for (int m = 1; m < 64; m <<= 1) s += __shfl_xor(s, m);
  __shared__ float part[4];
  if ((threadIdx.x & 63) == 0) part[threadIdx.x >> 6] = s;
  __syncthreads();
  if (threadIdx.x == 0)
    ymean[bc] = (part[0] + part[1] + part[2] + part[3]) * (1.0f / 4096.0f);
}

// ---------- K2: center, transpose [C][N]->[N][C], cast bf16, norm^2 partials ----------
__global__ __launch_bounds__(256) void k_pack(const float* __restrict__ X,
                                              const float* __restrict__ Y,
                                              const float* __restrict__ ymean,
                                              __hip_bfloat16* __restrict__ Xp,
                                              __hip_bfloat16* __restrict__ Yp,
                                              float* __restrict__ nx2,
                                              float* __restrict__ ny2) {
  const int n0 = blockIdx.x * 64, c0 = blockIdx.y * 64, b = blockIdx.z;
  __shared__ float tile[64][65];
  __shared__ float mu[64];
  const int t  = threadIdx.x;
  const int tc = t >> 6, tn = t & 63;              // read: 4 c-rows x 64 n
  const int oc = t & 63, on = t >> 6;              // write: 64 c, wave-per-n-row
  if (t < 64) mu[t] = ymean[b * 256 + c0 + t];
  __syncthreads();
  // X
  #pragma unroll 4
  for (int i = 0; i < 16; ++i) {
    int cl = i * 4 + tc;
    tile[cl][tn] = X[((size_t)b * 256 + c0 + cl) * 4096 + n0 + tn] - mu[cl];
  }
  __syncthreads();
  #pragma unroll 2
  for (int i = 0; i < 16; ++i) {
    int nl = i * 4 + on;
    float v = tile[oc][nl];
    Xp[((size_t)b * 4096 + n0 + nl) * 256 + c0 + oc] = __float2bfloat16(v);
    float sq = v * v;
    #pragma unroll
    for (int m = 1; m < 64; m <<= 1) sq += __shfl_xor(sq, m);
    if (oc == 0) atomicAdd(nx2 + b * 4096 + n0 + nl, sq);
  }
  __syncthreads();
  // Y
  #pragma unroll 4
  for (int i = 0; i < 16; ++i) {
    int cl = i * 4 + tc;
    tile[cl][tn] = Y[((size_t)b * 256 + c0 + cl) * 4096 + n0 + tn] - mu[cl];
  }
  __syncthreads();
  #pragma unroll 2
  for (int i = 0; i < 16; ++i) {
    int nl = i * 4 + on;
    float v = tile[oc][nl];
    Yp[((size_t)b * 4096 + n0 + nl) * 256 + c0 + oc] = __float2bfloat16(v);
    float sq = v * v;
    #pragma unroll
    for (int m = 1; m < 64; m <<= 1) sq += __shfl_xor(sq, m);
    if (oc == 0) atomicAdd(ny2 + b * 4096 + n0 + nl, sq);
  }
}

// ---------- K3: GEMM pass kernel (PASS=1 rowmax, PASS=2 expsum) ----------
// 256 blocks (1/CU): block = 128 rows x 2048 cols (half), K=256.
// 8 waves: rg = w>>2 (row half), cs = w&3 (64-col strip of 256-col macro-tile).
// Phases: 8 macro-tiles x 4 k-phases(64) = 32. Xs staged once (64KB, swizzled);
// Ys double-buffered [256m][64k] (2x32KB, swizzled). Counted vmcnt(4).
template<int PASS>
__global__ __launch_bounds__(512, 2) void k_pass(const __hip_bfloat16* __restrict__ Xp,
                                                 const __hip_bfloat16* __restrict__ Yp,
                                                 const float* __restrict__ nx2,
                                                 const float* __restrict__ ny2,
                                                 float* __restrict__ rmax_part,
                                                 float* __restrict__ ssum_part) {
  __shared__ __align__(16) char XsB[128 * 512];       // 64KB [row][512B k], swz (row&15)<<4
  __shared__ __align__(16) char YsB2[2][256 * 128];   // 2x32KB [m][128B k], swz (m&7)<<4
  __shared__ float invnyL[2048];
  __shared__ float redm[2][2][2][16][4];              // [rg][hi][ai][reg][cs]
  __shared__ float2 lammu[128];

  const int tid = threadIdx.x;
  const int lane = tid & 63;
  const int w = tid >> 6;
  const int rg = w >> 2, cs = w & 3;
  const int l31 = lane & 31, hi = lane >> 5;

  // block decode: XCD (=L%8) owns one (b,half) Y panel (1MB) for L2 locality
  const int L = blockIdx.x;
  const int b = (L & 7) >> 1, half = L & 1;
  const int rowtile = L >> 3;                         // [0,32)
  const int rowg0 = b * Nn + rowtile * 128;
  const int colg0 = half * 2048;

  const char* Xg = (const char*)(Xp + (size_t)rowg0 * Cn);
  const char* Yg = (const char*)(Yp + ((size_t)b * Nn + colg0) * Cn);

  // --- prologue: preload invny (and pass2 lam/mu) BEFORE any staging, so the
  // in-loop vmcnt count stays exact (no other VMEM in the main loop).
  #pragma unroll
  for (int i = 0; i < 4; ++i) {
    int c = tid + i * 512;
    invnyL[c] = rsqrtf(ny2[b * Nn + colg0 + c]);
  }
  if constexpr (PASS == 2) {
    if (tid < 128) {
      int rowg = rowg0 + tid;
      float mg = fmaxf(rmax_part[rowg], rmax_part[Bn * Nn + rowg]);
      float invnx = rsqrtf(nx2[rowg]);
      float smax = mg * invnx;
      float lam = (10.0f / (1.001f - smax)) * invnx * 1.44269504f;
      lammu[tid] = make_float2(lam, lam * mg);
    }
  }
  __syncthreads();

  float lamr[2][16], mur[2][16];
  if constexpr (PASS == 2) {
    #pragma unroll
    for (int ai = 0; ai < 2; ++ai)
      #pragma unroll
      for (int r = 0; r < 16; ++r) {
        int rloc = rg * 64 + ai * 32 + (r & 3) + 8 * (r >> 2) + 4 * hi;
        float2 lm = lammu[rloc];
        lamr[ai][r] = lm.x; mur[ai][r] = lm.y;
      }
  }

  // --- stage X once (8 GLD16/thread), then Ys phase 0 (4 GLD16/thread)
  #pragma unroll
  for (int s = 0; s < 8; ++s) {
    int row = s * 16 + (tid >> 5);
    GLD16(Xg + row * 512 + (((tid & 31) * 16) ^ ((row & 15) << 4)),
          XsB + s * 8192 + tid * 16);
  }
  int yoff[4];
  #pragma unroll
  for (int i = 0; i < 4; ++i) {
    int m = i * 64 + (tid >> 3);
    yoff[i] = m * 512 + (((tid & 7) * 16) ^ ((m & 7) << 4));
  }
  auto stageY = [&](int q) {
    const char* src = Yg + (size_t)((q >> 2) * 131072 + (q & 3) * 128);
    char* dst = YsB2[q & 1];
    #pragma unroll
    for (int i = 0; i < 4; ++i)
      GLD16(src + yoff[i], dst + i * 8192 + tid * 16);
  };
  stageY(0);

  // --- fragment address constants
  const int arow0 = rg * 64 + l31;          // + ai*32 (same swizzle nibble)
  const int aswz = (arow0 & 15) << 4;
  const int brow0 = cs * 64 + l31;
  const int bswz = (brow0 & 7) << 4;

  f32x16 acc[2][2];
  #pragma unroll
  for (int ai = 0; ai < 2; ++ai)
    #pragma unroll
    for (int bj = 0; bj < 2; ++bj) acc[ai][bj] = (f32x16)0.0f;
  float rmax[2][16], ssum[2][16];
  #pragma unroll
  for (int ai = 0; ai < 2; ++ai)
    #pragma unroll
    for (int r = 0; r < 16; ++r) { rmax[ai][r] = -3.0e38f; ssum[ai][r] = 0.f; }

  // --- main loop: stage(p+1); vmcnt(4); bar; ds_read+MFMA(+harvest); bar
  for (int p = 0; p < 32; ++p) {
    if (p < 31) { stageY(p + 1); asm volatile("s_waitcnt vmcnt(4)" ::: "memory"); }
    else        { asm volatile("s_waitcnt vmcnt(0)" ::: "memory"); }
    __builtin_amdgcn_s_barrier();

    const char* yb = YsB2[p & 1];
    const int kpB = (p & 3) << 7;
    __builtin_amdgcn_s_setprio(1);
    #pragma unroll
    for (int s = 0; s < 4; ++s) {
      const int kb = (s << 5) + (hi << 4);
      bf16x8 a0 = LDbf(XsB, arow0 * 512 + ((kpB + kb) ^ aswz));
      bf16x8 a1 = LDbf(XsB, (arow0 + 32) * 512 + ((kpB + kb) ^ aswz));
      bf16x8 b0 = LDbf(yb, brow0 * 128 + (kb ^ bswz));
      bf16x8 b1 = LDbf(yb, (brow0 + 32) * 128 + (kb ^ bswz));
      acc[0][0] = __builtin_amdgcn_mfma_f32_32x32x16_bf16(a0, b0, acc[0][0], 0, 0, 0);
      acc[0][1] = __builtin_amdgcn_mfma_f32_32x32x16_bf16(a0, b1, acc[0][1], 0, 0, 0);
      acc[1][0] = __builtin_amdgcn_mfma_f32_32x32x16_bf16(a1, b0, acc[1][0], 0, 0, 0);
      acc[1][1] = __builtin_amdgcn_mfma_f32_32x32x16_bf16(a1, b1, acc[1][1], 0, 0, 0);
    }
    __builtin_amdgcn_s_setprio(0);

    if ((p & 3) == 3) {                        // macro-tile done: harvest + reset
      const int cb = (p >> 2) * 256 + cs * 64 + l31;
      const float iny0 = invnyL[cb], iny1 = invnyL[cb + 32];
      #pragma unroll
      for (int ai = 0; ai < 2; ++ai)
        #pragma unroll
        for (int r = 0; r < 16; ++r) {
          if constexpr (PASS == 1) {
            rmax[ai][r] = fmaxf(rmax[ai][r],
                                fmaxf(acc[ai][0][r] * iny0, acc[ai][1][r] * iny1));
          } else {
            float e = exp2f(fmaf(lamr[ai][r], acc[ai][0][r] * iny0, -mur[ai][r]))
                    + exp2f(fmaf(lamr[ai][r], acc[ai][1][r] * iny1, -mur[ai][r]));
            ssum[ai][r] += e;
          }
          acc[ai][0][r] = 0.f; acc[ai][1][r] = 0.f;
        }
    }
    __builtin_amdgcn_s_barrier();
  }

  // --- epilogue: reduce within 32-lane halves, across cs-waves, write global
  #pragma unroll
  for (int ai = 0; ai < 2; ++ai)
    #pragma unroll
    for (int r = 0; r < 16; ++r) {
      float v = (PASS == 1) ? rmax[ai][r] : ssum[ai][r];
      #pragma unroll
      for (int m = 1; m < 32; m <<= 1) {
        float o = __shfl_xor(v, m);
        v = (PASS == 1) ? fmaxf(v, o) : (v + o);
      }
      if (l31 == 0) redm[rg][hi][ai][r][cs] = v;
    }
  __syncthreads();
  if (tid < 128) {
    const int rgg = tid >> 6, rr = tid & 63;
    const int aii = (rr >> 5) & 1, r32 = rr & 31;
    const int hh = (r32 >> 2) & 1;
    const int reg = (r32 & 3) | (((r32 >> 3) & 3) << 2);
    float v0 = redm[rgg][hh][aii][reg][0], v1 = redm[rgg][hh][aii][reg][1];
    float v2 = redm[rgg][hh][aii][reg][2], v3 = redm[rgg][hh][aii][reg][3];
    if constexpr (PASS == 1)
      rmax_part[half * (Bn * Nn) + rowg0 + tid] = fmaxf(fmaxf(v0, v1), fmaxf(v2, v3));
    else
      ssum_part[half * (Bn * Nn) + rowg0 + tid] = v0 + v1 + v2 + v3;
  }
}

// ---------- K4: loss = -log(mean_n 1/(ssum0+ssum1)) ----------
__global__ __launch_bounds__(256) void k_fin(const float* __restrict__ ssum_part,
                                             float* __restrict__ out) {
  const int b = blockIdx.x;
  float s = 0.f;
  #pragma unroll 4
  for (int i = 0; i < 16; ++i) {
    int row = b * Nn + threadIdx.x + i * 256;
    s += 1.0f / (ssum_part[row] + ssum_part[Bn * Nn + row]);
  }
  #pragma unroll
  for (int m = 1; m < 64; m <<= 1) s += __shfl_xor(s, m);
  __shared__ float part[4];
  if ((threadIdx.x & 63) == 0) part[threadIdx.x >> 6] = s;
  __syncthreads();
  if (threadIdx.x == 0)
    out[b] = -logf((part[0] + part[1] + part[2] + part[3]) * (1.0f / (float)Nn));
}

extern "C" void kernel_launch(void* const* d_in, const int* in_sizes, int n_in,
                              void* d_out, int out_size, void* d_ws, size_t ws_size,
                              hipStream_t stream) {
  const float* X = (const float*)d_in[0];
  const float* Y = (const float*)d_in[1];
  float* out = (float*)d_out;
  char* ws = (char*)d_ws;

  // workspace layout (~17.2 MB)
  __hip_bfloat16* Xp = (__hip_bfloat16*)ws;                       // 8MB [B][N][C]
  __hip_bfloat16* Yp = (__hip_bfloat16*)(ws + 8388608);           // 8MB
  float* nx2  = (float*)(ws + 16777216);                          // 16384 f32
  float* ny2  = nx2 + 16384;                                      // 16384 f32
  float* rmax = ny2 + 16384;                                      // [2][16384] f32
  float* ssum = rmax + 32768;                                     // [2][16384] f32
  float* ymean = ssum + 32768;                                    // 1024 f32

  hipMemsetAsync(nx2, 0, 2 * 16384 * sizeof(float), stream);      // nx2 + ny2
  k_mean  <<<Bn * Cn, 256, 0, stream>>>(Y, ymean);
  k_pack  <<<dim3(Nn / 64, Cn / 64, Bn), 256, 0, stream>>>(X, Y, ymean, Xp, Yp, nx2, ny2);
  k_pass<1><<<256, 512, 0, stream>>>(Xp, Yp, nx2, ny2, rmax, ssum);
  k_pass<2><<<256, 512, 0, stream>>>(Xp, Yp, nx2, ny2, rmax, ssum);
  k_fin   <<<Bn, 256, 0, stream>>>(ssum, out);
}